// Round 5
// baseline (609.283 us; speedup 1.0000x reference)
//
#include <hip/hip_runtime.h>

#define NN 100000
#define NE 1600000
#define N64 (NN * 64)

typedef __attribute__((ext_vector_type(8))) short bf16x8;
typedef __attribute__((ext_vector_type(4))) float fx4;

// ---- workspace layout (dword offsets) ----
#define W1D_OFF 0
#define W1S_OFF 448
#define W2D_OFF 896
#define W2S_OFF 4992
#define WB1F_OFF 9216                 // packed Wb frags layer1: 4096 dwords
#define WB2F_OFF 13312                // layer2: 4096 dwords
#define A_OFF   32768
#define B_OFF   (A_OFF + N64)
#define AGG_OFF (B_OFF + N64)
#define INT_OFF (AGG_OFF + N64)
#define CNT_I   0                     // counts   [100352]
#define CUR_I   100352                // cursor   [100352]
#define PART_I  200704                // partials [512]
#define BASE_I  201216                // base     [512]
#define SEDG_I  201728                // sorted int2{src,dst} [NE]

union FragU { int i[4]; bf16x8 f; };

// One prep kernel: zero histogram, precombine Wa weights, build Wb MFMA frags.
__global__ __launch_bounds__(256) void prep_all(
    const float* __restrict__ W1a, const float* __restrict__ W1b,
    const float* __restrict__ W2a, const float* __restrict__ W2b,
    float* __restrict__ ws, int* __restrict__ counts)
{
    int t = blockIdx.x * 256 + threadIdx.x;
    if (t < 100352) counts[t] = 0;
    if (t < 448) {
        float top = W1a[t], bot = W1a[448 + t];
        ws[W1D_OFF + t] = top - bot;
        ws[W1S_OFF + t] = bot;
    }
    if (t < 4096) {
        float top = W2a[t], bot = W2a[4096 + t];
        ws[W2D_OFF + t] = top - bot;
        ws[W2S_OFF + t] = bot;
    }
    // Wb fragments (hi/lo truncation split):
    // int4 index r = mat*512 + ks*256 + nt*64 + lane; lane gives k=(lane>>4)*8+j+32ks,
    // n=(lane&15)+16nt, j packed 2 per dword.
    if (t < 2048) {
        int layer = t >> 10;
        int r = t & 1023;
        int ks = (r >> 8) & 1, nt = (r >> 6) & 3, lane = r & 63, mat = r >> 9;
        const float* Wb = layer ? W2b : W1b;
        int* out = (int*)(ws + (layer ? WB2F_OFF : WB1F_OFF));
        int quad = lane >> 4, c = lane & 15, n = nt * 16 + c;
        unsigned dw[4];
#pragma unroll
        for (int d = 0; d < 4; ++d) {
            unsigned v[2];
#pragma unroll
            for (int e = 0; e < 2; ++e) {
                int k = quad * 8 + d * 2 + e + 32 * ks;
                float w = Wb[k * 64 + n];
                unsigned u = __float_as_uint(w);
                if (mat == 0) v[e] = u >> 16;                        // hi = trunc
                else {
                    float lo = w - __uint_as_float(u & 0xFFFF0000u); // exact residual
                    v[e] = __float_as_uint(lo) >> 16;
                }
            }
            dw[d] = (v[1] << 16) | v[0];
        }
        ((int4*)out)[r] = make_int4((int)dw[0], (int)dw[1], (int)dw[2], (int)dw[3]);
    }
}

// A[i] = x_i @ Wd + ba ; B[i] = x_i @ Ws   (7-ch input); also zero AGG row.
__global__ __launch_bounds__(256) void node_mlp1(
    const float* __restrict__ x, const float* __restrict__ Wd,
    const float* __restrict__ Ws, const float* __restrict__ ba,
    float* __restrict__ A, float* __restrict__ Bv, float* __restrict__ agg)
{
    int i = blockIdx.x * 256 + threadIdx.x;
    if (i >= NN) return;
    float xv[7];
#pragma unroll
    for (int k = 0; k < 7; ++k) xv[k] = x[i * 7 + k];
    float4* pa = (float4*)(A + (size_t)i * 64);
    float4* pb = (float4*)(Bv + (size_t)i * 64);
    float4* pz = (float4*)(agg + (size_t)i * 64);
#pragma unroll
    for (int q = 0; q < 16; ++q) pz[q] = make_float4(0.f, 0.f, 0.f, 0.f);
#pragma unroll
    for (int half = 0; half < 2; ++half) {
        float acc[32];
#pragma unroll
        for (int c = 0; c < 32; ++c) acc[c] = ba[half * 32 + c];
#pragma unroll
        for (int k = 0; k < 7; ++k)
#pragma unroll
            for (int c = 0; c < 32; ++c)
                acc[c] = fmaf(xv[k], Wd[k * 64 + half * 32 + c], acc[c]);
#pragma unroll
        for (int q = 0; q < 8; ++q)
            pa[half * 8 + q] = make_float4(acc[q*4], acc[q*4+1], acc[q*4+2], acc[q*4+3]);
#pragma unroll
        for (int c = 0; c < 32; ++c) acc[c] = 0.0f;
#pragma unroll
        for (int k = 0; k < 7; ++k)
#pragma unroll
            for (int c = 0; c < 32; ++c)
                acc[c] = fmaf(xv[k], Ws[k * 64 + half * 32 + c], acc[c]);
#pragma unroll
        for (int q = 0; q < 8; ++q)
            pb[half * 8 + q] = make_float4(acc[q*4], acc[q*4+1], acc[q*4+2], acc[q*4+3]);
    }
}

// A[i] = g_i @ Wd + ba2 ; B[i] = g_i @ Ws ; then zero g row (re-arm AGG for layer 2)
__global__ __launch_bounds__(256) void node_mlp2(
    float* __restrict__ g, const float* __restrict__ Wd,
    const float* __restrict__ Ws, const float* __restrict__ ba2,
    float* __restrict__ A, float* __restrict__ Bv)
{
    int i = blockIdx.x * 256 + threadIdx.x;
    if (i >= NN) return;
    float gv[64];
    float4* pg = (float4*)(g + (size_t)i * 64);
#pragma unroll
    for (int q = 0; q < 16; ++q) {
        float4 v = pg[q];
        gv[q*4+0] = v.x; gv[q*4+1] = v.y; gv[q*4+2] = v.z; gv[q*4+3] = v.w;
    }
#pragma unroll
    for (int q = 0; q < 16; ++q) pg[q] = make_float4(0.f, 0.f, 0.f, 0.f);
    float4* pa = (float4*)(A + (size_t)i * 64);
    float4* pb = (float4*)(Bv + (size_t)i * 64);
#pragma unroll
    for (int half = 0; half < 2; ++half) {
        float acc[32];
#pragma unroll
        for (int c = 0; c < 32; ++c) acc[c] = ba2[half * 32 + c];
#pragma unroll
        for (int j = 0; j < 64; ++j)
#pragma unroll
            for (int c = 0; c < 32; ++c)
                acc[c] = fmaf(gv[j], Wd[j * 64 + half * 32 + c], acc[c]);
#pragma unroll
        for (int q = 0; q < 8; ++q)
            pa[half * 8 + q] = make_float4(acc[q*4], acc[q*4+1], acc[q*4+2], acc[q*4+3]);
#pragma unroll
        for (int c = 0; c < 32; ++c) acc[c] = 0.0f;
#pragma unroll
        for (int j = 0; j < 64; ++j)
#pragma unroll
            for (int c = 0; c < 32; ++c)
                acc[c] = fmaf(gv[j], Ws[j * 64 + half * 32 + c], acc[c]);
#pragma unroll
        for (int q = 0; q < 8; ++q)
            pb[half * 8 + q] = make_float4(acc[q*4], acc[q*4+1], acc[q*4+2], acc[q*4+3]);
    }
}

// ---- counting sort of edges by dst ----
// 8 edges/thread: int4-pair loads, 8 independent non-returning atomics.
__global__ __launch_bounds__(256) void k_hist(const int* __restrict__ dst, int* __restrict__ counts)
{
    int e0 = (blockIdx.x * 256 + threadIdx.x) * 8;
    if (e0 >= NE) return;                        // NE % 8 == 0
    int4 d0 = ((const int4*)(dst + e0))[0];
    int4 d1 = ((const int4*)(dst + e0))[1];
    atomicAdd(&counts[d0.x], 1); atomicAdd(&counts[d0.y], 1);
    atomicAdd(&counts[d0.z], 1); atomicAdd(&counts[d0.w], 1);
    atomicAdd(&counts[d1.x], 1); atomicAdd(&counts[d1.y], 1);
    atomicAdd(&counts[d1.z], 1); atomicAdd(&counts[d1.w], 1);
}

__global__ __launch_bounds__(256) void k_scanA(
    const int* __restrict__ counts, int* __restrict__ cursor, int* __restrict__ partials)
{
    __shared__ int sh[256];
    int t = threadIdx.x, i = blockIdx.x * 256 + t;
    int c = counts[i];
    sh[t] = c; __syncthreads();
#pragma unroll
    for (int off = 1; off < 256; off <<= 1) {
        int v = (t >= off) ? sh[t - off] : 0;
        __syncthreads();
        sh[t] += v;
        __syncthreads();
    }
    cursor[i] = sh[t] - c;
    if (t == 255) partials[blockIdx.x] = sh[t];
}

__global__ __launch_bounds__(512) void k_scanB(const int* __restrict__ partials, int* __restrict__ base)
{
    __shared__ int sh[512];
    int t = threadIdx.x;
    int c = (t < 392) ? partials[t] : 0;
    sh[t] = c; __syncthreads();
#pragma unroll
    for (int off = 1; off < 512; off <<= 1) {
        int v = (t >= off) ? sh[t - off] : 0;
        __syncthreads();
        sh[t] += v;
        __syncthreads();
    }
    if (t < 392) base[t] = sh[t] - c;
}

// 8 edges/thread: 8 independent returning atomics, then 8 independent stores
// (hides the ~600-900 cyc fabric-atomic round-trip 8x better than 1/thread).
__global__ __launch_bounds__(256) void k_scatter(
    const int* __restrict__ src, const int* __restrict__ dst,
    int* __restrict__ cursor, const int* __restrict__ base,
    int2* __restrict__ sedge)
{
    int e0 = (blockIdx.x * 256 + threadIdx.x) * 8;
    if (e0 >= NE) return;                        // NE % 8 == 0
    int4 d0 = ((const int4*)(dst + e0))[0];
    int4 d1 = ((const int4*)(dst + e0))[1];
    int4 s0 = ((const int4*)(src + e0))[0];
    int4 s1 = ((const int4*)(src + e0))[1];
    int dd[8] = { d0.x, d0.y, d0.z, d0.w, d1.x, d1.y, d1.z, d1.w };
    int ss[8] = { s0.x, s0.y, s0.z, s0.w, s1.x, s1.y, s1.z, s1.w };
    int pos[8];
#pragma unroll
    for (int j = 0; j < 8; ++j)
        pos[j] = atomicAdd(&cursor[dd[j]], 1);
#pragma unroll
    for (int j = 0; j < 8; ++j)
        sedge[pos[j] + base[dd[j] >> 8]] = make_int2(ss[j], dd[j]);
}

// MFMA edge layer, direct per-lane fragment gather (no staging LDS).
__global__ __launch_bounds__(256, 3) void edge_layer_mfma(
    const float* __restrict__ A, const float* __restrict__ Bv,
    const int2* __restrict__ se,
    const int* __restrict__ wbf, const float* __restrict__ bb,
    unsigned int* __restrict__ agg)
{
    __shared__ int lds[4][1152];           // per wave: 128 idx dw + 1024 chunk dw
    const int tid = threadIdx.x;
    const int wv = tid >> 6, lane = tid & 63;
    int* idxb = lds[wv];
    int* chunk = lds[wv] + 128;
    const int quad = lane >> 4, c15 = lane & 15;
    const int base = (blockIdx.x * 4 + wv) * 64;

    int2 ed = se[base + lane];
    ((int2*)idxb)[lane] = ed;              // ds_write_b64; same-wave, no barrier
    const int d_all = ed.y;

    fx4 acc[4][4];
#pragma unroll
    for (int mt = 0; mt < 4; ++mt)
#pragma unroll
        for (int nt = 0; nt < 4; ++nt)
            acc[mt][nt] = (fx4){0.f, 0.f, 0.f, 0.f};

    int2 es[4];
#pragma unroll
    for (int mt = 0; mt < 4; ++mt)
        es[mt] = ((const int2*)idxb)[mt * 16 + c15];   // same-address broadcast per quad

#pragma unroll
    for (int ks = 0; ks < 2; ++ks) {
        bf16x8 wh[4], wl[4];
#pragma unroll
        for (int nt = 0; nt < 4; ++nt) {
            int4 v = ((const int4*)wbf)[(ks * 4 + nt) * 64 + lane];          // mat=0
            FragU u; u.i[0] = v.x; u.i[1] = v.y; u.i[2] = v.z; u.i[3] = v.w;
            wh[nt] = u.f;
            int4 v2 = ((const int4*)wbf)[((2 + ks) * 4 + nt) * 64 + lane];   // mat=1
            FragU u2; u2.i[0] = v2.x; u2.i[1] = v2.y; u2.i[2] = v2.z; u2.i[3] = v2.w;
            wl[nt] = u2.f;
        }
#pragma unroll
        for (int mt = 0; mt < 4; ++mt) {
            const float4* pa = (const float4*)(A + (size_t)es[mt].y * 64 + ks * 32 + quad * 8);
            const float4* pb = (const float4*)(Bv + (size_t)es[mt].x * 64 + ks * 32 + quad * 8);
            float4 a0 = pa[0], a1 = pa[1];
            float4 b0 = pb[0], b1 = pb[1];
            float t[8];
            t[0] = fmaxf(a0.x + b0.x, 0.f); t[1] = fmaxf(a0.y + b0.y, 0.f);
            t[2] = fmaxf(a0.z + b0.z, 0.f); t[3] = fmaxf(a0.w + b0.w, 0.f);
            t[4] = fmaxf(a1.x + b1.x, 0.f); t[5] = fmaxf(a1.y + b1.y, 0.f);
            t[6] = fmaxf(a1.z + b1.z, 0.f); t[7] = fmaxf(a1.w + b1.w, 0.f);
            FragU uh, ul;
#pragma unroll
            for (int d2 = 0; d2 < 4; ++d2) {
                unsigned u0 = __float_as_uint(t[2 * d2]);
                unsigned u1 = __float_as_uint(t[2 * d2 + 1]);
                uh.i[d2] = (int)((u1 & 0xFFFF0000u) | (u0 >> 16));
                float l0 = t[2 * d2]     - __uint_as_float(u0 & 0xFFFF0000u);
                float l1 = t[2 * d2 + 1] - __uint_as_float(u1 & 0xFFFF0000u);
                ul.i[d2] = (int)((__float_as_uint(l1) & 0xFFFF0000u) |
                                 (__float_as_uint(l0) >> 16));
            }
            bf16x8 fah = uh.f, fal = ul.f;
#pragma unroll
            for (int nt = 0; nt < 4; ++nt) {
                acc[mt][nt] = __builtin_amdgcn_mfma_f32_16x16x32_bf16(fah, wh[nt], acc[mt][nt], 0, 0, 0);
                acc[mt][nt] = __builtin_amdgcn_mfma_f32_16x16x32_bf16(fah, wl[nt], acc[mt][nt], 0, 0, 0);
                acc[mt][nt] = __builtin_amdgcn_mfma_f32_16x16x32_bf16(fal, wh[nt], acc[mt][nt], 0, 0, 0);
            }
        }
    }

    // epilogue: bias+relu, 16-edge LDS chunks (2-way-max bank swizzle), segmented max
    float bbv[4];
#pragma unroll
    for (int nt = 0; nt < 4; ++nt) bbv[nt] = bb[nt * 16 + c15];

    int dprev = __builtin_amdgcn_readlane(d_all, 0);
    float run = 0.f;
#pragma unroll
    for (int mt = 0; mt < 4; ++mt) {
#pragma unroll
        for (int nt = 0; nt < 4; ++nt)
#pragma unroll
            for (int r = 0; r < 4; ++r) {
                int ee = mt * 16 + quad * 4 + r;
                int ch = nt * 16 + c15;
                float h = fmaxf(acc[mt][nt][r] + bbv[nt], 0.f);
                chunk[(ee & 15) * 64 + ((ch + 4 * ee) & 63)] = __float_as_int(h);
            }
#pragma unroll
        for (int i = 0; i < 16; ++i) {
            int ee = mt * 16 + i;
            float v = __int_as_float(chunk[i * 64 + ((lane + 4 * ee) & 63)]);
            int dd = __builtin_amdgcn_readlane(d_all, ee);
            if (dd != dprev) {
                atomicMax(&agg[(size_t)dprev * 64 + lane], __float_as_uint(run));
                run = 0.f; dprev = dd;
            }
            run = fmaxf(run, v);
        }
    }
    atomicMax(&agg[(size_t)dprev * 64 + lane], __float_as_uint(run));
}

// out[i] = h2[i,:] @ Wl + bl
__global__ __launch_bounds__(256) void final_linear(
    const float* __restrict__ h2, const float* __restrict__ Wl,
    const float* __restrict__ bl, float* __restrict__ out)
{
    int i = blockIdx.x * 256 + threadIdx.x;
    if (i >= NN) return;
    const float4* row = (const float4*)(h2 + (size_t)i * 64);
    float acc = bl[0];
#pragma unroll
    for (int q = 0; q < 16; ++q) {
        float4 v = row[q];
        acc = fmaf(v.x, Wl[q * 4 + 0], acc);
        acc = fmaf(v.y, Wl[q * 4 + 1], acc);
        acc = fmaf(v.z, Wl[q * 4 + 2], acc);
        acc = fmaf(v.w, Wl[q * 4 + 3], acc);
    }
    out[i] = acc;
}

extern "C" void kernel_launch(void* const* d_in, const int* in_sizes, int n_in,
                              void* d_out, int out_size, void* d_ws, size_t ws_size,
                              hipStream_t stream)
{
    const float* x   = (const float*)d_in[0];
    const int*   ei  = (const int*)d_in[1];
    const float* W1a = (const float*)d_in[2];
    const float* b1a = (const float*)d_in[3];
    const float* W1b = (const float*)d_in[4];
    const float* b1b = (const float*)d_in[5];
    const float* W2a = (const float*)d_in[6];
    const float* b2a = (const float*)d_in[7];
    const float* W2b = (const float*)d_in[8];
    const float* b2b = (const float*)d_in[9];
    const float* Wl  = (const float*)d_in[10];
    const float* bl  = (const float*)d_in[11];

    const int* src = ei;
    const int* dst = ei + NE;

    float* ws = (float*)d_ws;
    float* A    = ws + A_OFF;
    float* B    = ws + B_OFF;
    unsigned int* AGG = (unsigned int*)(ws + AGG_OFF);
    int* ib = (int*)(ws + INT_OFF);
    int* counts   = ib + CNT_I;
    int* cursor   = ib + CUR_I;
    int* partials = ib + PART_I;
    int* base     = ib + BASE_I;
    int2* sedge   = (int2*)(ib + SEDG_I);

    prep_all<<<392, 256, 0, stream>>>(W1a, W1b, W2a, W2b, ws, counts);
    node_mlp1<<<391, 256, 0, stream>>>(x, ws + W1D_OFF, ws + W1S_OFF, b1a, A, B, (float*)AGG);

    k_hist   <<<782, 256, 0, stream>>>(dst, counts);
    k_scanA  <<<392, 256, 0, stream>>>(counts, cursor, partials);
    k_scanB  <<<1, 512, 0, stream>>>(partials, base);
    k_scatter<<<782, 256, 0, stream>>>(src, dst, cursor, base, sedge);

    edge_layer_mfma<<<NE / 256, 256, 0, stream>>>(A, B, sedge,
                                                  (const int*)(ws + WB1F_OFF), b1b, AGG);

    node_mlp2<<<391, 256, 0, stream>>>((float*)AGG, ws + W2D_OFF, ws + W2S_OFF, b2a, A, B);

    edge_layer_mfma<<<NE / 256, 256, 0, stream>>>(A, B, sedge,
                                                  (const int*)(ws + WB2F_OFF), b2b, AGG);

    final_linear<<<391, 256, 0, stream>>>((const float*)AGG, Wl, bl, (float*)d_out);
}

// Round 6
// 458.809 us; speedup vs baseline: 1.3280x; 1.3280x over previous
//
#include <hip/hip_runtime.h>

#define NN 100000
#define NE 1600000
#define N64 (NN * 64)
#define NB 196                        // buckets = dst>>9 (100000/512)
#define CAP 9216                      // bucket capacity (mean 8192, +11 sigma)

typedef __attribute__((ext_vector_type(8))) short bf16x8;
typedef __attribute__((ext_vector_type(4))) float fx4;

// ---- workspace layout (dword offsets) ----
#define W1D_OFF 0
#define W1S_OFF 448
#define W2D_OFF 896
#define W2S_OFF 4992
#define WB1F_OFF 9216                 // packed Wb frags layer1: 4096 dwords
#define WB2F_OFF 13312                // layer2: 4096 dwords
#define GCUR_OFF 17408                // bucket cursors [256]
#define A_OFF   32768
#define B_OFF   (A_OFF + N64)
#define AGG_OFF (B_OFF + N64)
#define P1_OFF  (AGG_OFF + N64)       // int2[NB*CAP] bucket staging
#define SEDG_OFF (P1_OFF + 2 * NB * CAP)  // int2[NE] sorted edges

union FragU { int i[4]; bf16x8 f; };

// One prep kernel: zero bucket cursors, precombine Wa weights, build Wb MFMA frags.
__global__ __launch_bounds__(256) void prep_all(
    const float* __restrict__ W1a, const float* __restrict__ W1b,
    const float* __restrict__ W2a, const float* __restrict__ W2b,
    float* __restrict__ ws, int* __restrict__ gcur)
{
    int t = blockIdx.x * 256 + threadIdx.x;
    if (t < 256) gcur[t] = 0;
    if (t < 448) {
        float top = W1a[t], bot = W1a[448 + t];
        ws[W1D_OFF + t] = top - bot;
        ws[W1S_OFF + t] = bot;
    }
    if (t < 4096) {
        float top = W2a[t], bot = W2a[4096 + t];
        ws[W2D_OFF + t] = top - bot;
        ws[W2S_OFF + t] = bot;
    }
    // Wb fragments (hi/lo truncation split):
    // int4 index r = mat*512 + ks*256 + nt*64 + lane; lane gives k=(lane>>4)*8+j+32ks,
    // n=(lane&15)+16nt, j packed 2 per dword.
    if (t < 2048) {
        int layer = t >> 10;
        int r = t & 1023;
        int ks = (r >> 8) & 1, nt = (r >> 6) & 3, lane = r & 63, mat = r >> 9;
        const float* Wb = layer ? W2b : W1b;
        int* out = (int*)(ws + (layer ? WB2F_OFF : WB1F_OFF));
        int quad = lane >> 4, c = lane & 15, n = nt * 16 + c;
        unsigned dw[4];
#pragma unroll
        for (int d = 0; d < 4; ++d) {
            unsigned v[2];
#pragma unroll
            for (int e = 0; e < 2; ++e) {
                int k = quad * 8 + d * 2 + e + 32 * ks;
                float w = Wb[k * 64 + n];
                unsigned u = __float_as_uint(w);
                if (mat == 0) v[e] = u >> 16;                        // hi = trunc
                else {
                    float lo = w - __uint_as_float(u & 0xFFFF0000u); // exact residual
                    v[e] = __float_as_uint(lo) >> 16;
                }
            }
            dw[d] = (v[1] << 16) | v[0];
        }
        ((int4*)out)[r] = make_int4((int)dw[0], (int)dw[1], (int)dw[2], (int)dw[3]);
    }
}

// A[i] = x_i @ Wd + ba ; B[i] = x_i @ Ws   (7-ch input); also zero AGG row.
__global__ __launch_bounds__(256) void node_mlp1(
    const float* __restrict__ x, const float* __restrict__ Wd,
    const float* __restrict__ Ws, const float* __restrict__ ba,
    float* __restrict__ A, float* __restrict__ Bv, float* __restrict__ agg)
{
    int i = blockIdx.x * 256 + threadIdx.x;
    if (i >= NN) return;
    float xv[7];
#pragma unroll
    for (int k = 0; k < 7; ++k) xv[k] = x[i * 7 + k];
    float4* pa = (float4*)(A + (size_t)i * 64);
    float4* pb = (float4*)(Bv + (size_t)i * 64);
    float4* pz = (float4*)(agg + (size_t)i * 64);
#pragma unroll
    for (int q = 0; q < 16; ++q) pz[q] = make_float4(0.f, 0.f, 0.f, 0.f);
#pragma unroll
    for (int half = 0; half < 2; ++half) {
        float acc[32];
#pragma unroll
        for (int c = 0; c < 32; ++c) acc[c] = ba[half * 32 + c];
#pragma unroll
        for (int k = 0; k < 7; ++k)
#pragma unroll
            for (int c = 0; c < 32; ++c)
                acc[c] = fmaf(xv[k], Wd[k * 64 + half * 32 + c], acc[c]);
#pragma unroll
        for (int q = 0; q < 8; ++q)
            pa[half * 8 + q] = make_float4(acc[q*4], acc[q*4+1], acc[q*4+2], acc[q*4+3]);
#pragma unroll
        for (int c = 0; c < 32; ++c) acc[c] = 0.0f;
#pragma unroll
        for (int k = 0; k < 7; ++k)
#pragma unroll
            for (int c = 0; c < 32; ++c)
                acc[c] = fmaf(xv[k], Ws[k * 64 + half * 32 + c], acc[c]);
#pragma unroll
        for (int q = 0; q < 8; ++q)
            pb[half * 8 + q] = make_float4(acc[q*4], acc[q*4+1], acc[q*4+2], acc[q*4+3]);
    }
}

// A[i] = g_i @ Wd + ba2 ; B[i] = g_i @ Ws ; then zero g row (re-arm AGG for layer 2)
__global__ __launch_bounds__(256) void node_mlp2(
    float* __restrict__ g, const float* __restrict__ Wd,
    const float* __restrict__ Ws, const float* __restrict__ ba2,
    float* __restrict__ A, float* __restrict__ Bv)
{
    int i = blockIdx.x * 256 + threadIdx.x;
    if (i >= NN) return;
    float gv[64];
    float4* pg = (float4*)(g + (size_t)i * 64);
#pragma unroll
    for (int q = 0; q < 16; ++q) {
        float4 v = pg[q];
        gv[q*4+0] = v.x; gv[q*4+1] = v.y; gv[q*4+2] = v.z; gv[q*4+3] = v.w;
    }
#pragma unroll
    for (int q = 0; q < 16; ++q) pg[q] = make_float4(0.f, 0.f, 0.f, 0.f);
    float4* pa = (float4*)(A + (size_t)i * 64);
    float4* pb = (float4*)(Bv + (size_t)i * 64);
#pragma unroll
    for (int half = 0; half < 2; ++half) {
        float acc[32];
#pragma unroll
        for (int c = 0; c < 32; ++c) acc[c] = ba2[half * 32 + c];
#pragma unroll
        for (int j = 0; j < 64; ++j)
#pragma unroll
            for (int c = 0; c < 32; ++c)
                acc[c] = fmaf(gv[j], Wd[j * 64 + half * 32 + c], acc[c]);
#pragma unroll
        for (int q = 0; q < 8; ++q)
            pa[half * 8 + q] = make_float4(acc[q*4], acc[q*4+1], acc[q*4+2], acc[q*4+3]);
#pragma unroll
        for (int c = 0; c < 32; ++c) acc[c] = 0.0f;
#pragma unroll
        for (int j = 0; j < 64; ++j)
#pragma unroll
            for (int c = 0; c < 32; ++c)
                acc[c] = fmaf(gv[j], Ws[j * 64 + half * 32 + c], acc[c]);
#pragma unroll
        for (int q = 0; q < 8; ++q)
            pb[half * 8 + q] = make_float4(acc[q*4], acc[q*4+1], acc[q*4+2], acc[q*4+3]);
    }
}

// ---- two-pass edge sort by dst ----
// Pass 1: block-level multisplit into NB coarse buckets (dst>>9). LDS histogram,
// one reserving global atomic per bucket per block, then LDS-cursor placement.
// Per-block bucket runs are ~64B contiguous -> lines fill within one L2 window.
__global__ __launch_bounds__(256) void k_bucket(
    const int* __restrict__ src, const int* __restrict__ dst,
    int* __restrict__ gcur, int2* __restrict__ p1)
{
    __shared__ int cnt[NB];
    __shared__ int cur[NB];
    const int t = threadIdx.x;
    const int e0 = (blockIdx.x * 256 + t) * 8;
    const bool ok = (e0 < NE);                   // NE % 8 == 0
    if (t < NB) cnt[t] = 0;
    int ss[8], dd[8], bk[8];
    if (ok) {
        int4 d0 = ((const int4*)(dst + e0))[0];
        int4 d1 = ((const int4*)(dst + e0))[1];
        int4 s0 = ((const int4*)(src + e0))[0];
        int4 s1 = ((const int4*)(src + e0))[1];
        dd[0]=d0.x; dd[1]=d0.y; dd[2]=d0.z; dd[3]=d0.w;
        dd[4]=d1.x; dd[5]=d1.y; dd[6]=d1.z; dd[7]=d1.w;
        ss[0]=s0.x; ss[1]=s0.y; ss[2]=s0.z; ss[3]=s0.w;
        ss[4]=s1.x; ss[5]=s1.y; ss[6]=s1.z; ss[7]=s1.w;
    }
    __syncthreads();
    if (ok) {
#pragma unroll
        for (int j = 0; j < 8; ++j) { bk[j] = dd[j] >> 9; atomicAdd(&cnt[bk[j]], 1); }
    }
    __syncthreads();
    if (t < NB) cur[t] = atomicAdd(&gcur[t], cnt[t]);   // reserve block's ranges
    __syncthreads();
    if (ok) {
#pragma unroll
        for (int j = 0; j < 8; ++j) {
            int pos = atomicAdd(&cur[bk[j]], 1);
            p1[(size_t)bk[j] * CAP + pos] = make_int2(ss[j], dd[j]);
        }
    }
}

// Pass 2: one block per bucket. Counting-sort by low 9 bits of dst in LDS;
// dense output at exclusive-scanned bucket base. Bucket data is L2-hot.
__global__ __launch_bounds__(256) void k_sortbkt(
    const int2* __restrict__ p1, const int* __restrict__ gcnt,
    int2* __restrict__ sedge)
{
    __shared__ int sz[256];
    __shared__ int cnt[512];
    __shared__ int cur[512];
    __shared__ int pairb[256];
    const int b = blockIdx.x, t = threadIdx.x;
    sz[t] = (t < NB) ? gcnt[t] : 0;
    cnt[t] = 0; cnt[t + 256] = 0;
    __syncthreads();
#pragma unroll
    for (int off = 1; off < 256; off <<= 1) {       // inclusive scan of bucket sizes
        int u = (t >= off) ? sz[t - off] : 0;
        __syncthreads();
        sz[t] += u;
        __syncthreads();
    }
    const int myBase = (b == 0) ? 0 : sz[b - 1];
    const int mySize = gcnt[b];
    const int2* bp = p1 + (size_t)b * CAP;
    for (int i = t; i < mySize; i += 256) atomicAdd(&cnt[bp[i].y & 511], 1);
    __syncthreads();
    pairb[t] = cnt[2 * t] + cnt[2 * t + 1];
    __syncthreads();
#pragma unroll
    for (int off = 1; off < 256; off <<= 1) {       // scan pair-sums
        int u = (t >= off) ? pairb[t - off] : 0;
        __syncthreads();
        pairb[t] += u;
        __syncthreads();
    }
    int ex = (t == 0) ? 0 : pairb[t - 1];
    cur[2 * t] = ex;
    cur[2 * t + 1] = ex + cnt[2 * t];
    __syncthreads();
    for (int i = t; i < mySize; i += 256) {
        int2 e = bp[i];
        int pos = atomicAdd(&cur[e.y & 511], 1);
        sedge[(size_t)myBase + pos] = e;
    }
}

// MFMA edge layer, direct per-lane fragment gather (no staging LDS).
__global__ __launch_bounds__(256, 3) void edge_layer_mfma(
    const float* __restrict__ A, const float* __restrict__ Bv,
    const int2* __restrict__ se,
    const int* __restrict__ wbf, const float* __restrict__ bb,
    unsigned int* __restrict__ agg)
{
    __shared__ int lds[4][1152];           // per wave: 128 idx dw + 1024 chunk dw
    const int tid = threadIdx.x;
    const int wv = tid >> 6, lane = tid & 63;
    int* idxb = lds[wv];
    int* chunk = lds[wv] + 128;
    const int quad = lane >> 4, c15 = lane & 15;
    const int base = (blockIdx.x * 4 + wv) * 64;

    int2 ed = se[base + lane];
    ((int2*)idxb)[lane] = ed;              // ds_write_b64; same-wave, no barrier
    const int d_all = ed.y;

    fx4 acc[4][4];
#pragma unroll
    for (int mt = 0; mt < 4; ++mt)
#pragma unroll
        for (int nt = 0; nt < 4; ++nt)
            acc[mt][nt] = (fx4){0.f, 0.f, 0.f, 0.f};

    int2 es[4];
#pragma unroll
    for (int mt = 0; mt < 4; ++mt)
        es[mt] = ((const int2*)idxb)[mt * 16 + c15];   // same-address broadcast per quad

#pragma unroll
    for (int ks = 0; ks < 2; ++ks) {
        bf16x8 wh[4], wl[4];
#pragma unroll
        for (int nt = 0; nt < 4; ++nt) {
            int4 v = ((const int4*)wbf)[(ks * 4 + nt) * 64 + lane];          // mat=0
            FragU u; u.i[0] = v.x; u.i[1] = v.y; u.i[2] = v.z; u.i[3] = v.w;
            wh[nt] = u.f;
            int4 v2 = ((const int4*)wbf)[((2 + ks) * 4 + nt) * 64 + lane];   // mat=1
            FragU u2; u2.i[0] = v2.x; u2.i[1] = v2.y; u2.i[2] = v2.z; u2.i[3] = v2.w;
            wl[nt] = u2.f;
        }
#pragma unroll
        for (int mt = 0; mt < 4; ++mt) {
            const float4* pa = (const float4*)(A + (size_t)es[mt].y * 64 + ks * 32 + quad * 8);
            const float4* pb = (const float4*)(Bv + (size_t)es[mt].x * 64 + ks * 32 + quad * 8);
            float4 a0 = pa[0], a1 = pa[1];
            float4 b0 = pb[0], b1 = pb[1];
            float t[8];
            t[0] = fmaxf(a0.x + b0.x, 0.f); t[1] = fmaxf(a0.y + b0.y, 0.f);
            t[2] = fmaxf(a0.z + b0.z, 0.f); t[3] = fmaxf(a0.w + b0.w, 0.f);
            t[4] = fmaxf(a1.x + b1.x, 0.f); t[5] = fmaxf(a1.y + b1.y, 0.f);
            t[6] = fmaxf(a1.z + b1.z, 0.f); t[7] = fmaxf(a1.w + b1.w, 0.f);
            FragU uh, ul;
#pragma unroll
            for (int d2 = 0; d2 < 4; ++d2) {
                unsigned u0 = __float_as_uint(t[2 * d2]);
                unsigned u1 = __float_as_uint(t[2 * d2 + 1]);
                uh.i[d2] = (int)((u1 & 0xFFFF0000u) | (u0 >> 16));
                float l0 = t[2 * d2]     - __uint_as_float(u0 & 0xFFFF0000u);
                float l1 = t[2 * d2 + 1] - __uint_as_float(u1 & 0xFFFF0000u);
                ul.i[d2] = (int)((__float_as_uint(l1) & 0xFFFF0000u) |
                                 (__float_as_uint(l0) >> 16));
            }
            bf16x8 fah = uh.f, fal = ul.f;
#pragma unroll
            for (int nt = 0; nt < 4; ++nt) {
                acc[mt][nt] = __builtin_amdgcn_mfma_f32_16x16x32_bf16(fah, wh[nt], acc[mt][nt], 0, 0, 0);
                acc[mt][nt] = __builtin_amdgcn_mfma_f32_16x16x32_bf16(fah, wl[nt], acc[mt][nt], 0, 0, 0);
                acc[mt][nt] = __builtin_amdgcn_mfma_f32_16x16x32_bf16(fal, wh[nt], acc[mt][nt], 0, 0, 0);
            }
        }
    }

    // epilogue: bias+relu, 16-edge LDS chunks (2-way-max bank swizzle), segmented max
    float bbv[4];
#pragma unroll
    for (int nt = 0; nt < 4; ++nt) bbv[nt] = bb[nt * 16 + c15];

    int dprev = __builtin_amdgcn_readlane(d_all, 0);
    float run = 0.f;
#pragma unroll
    for (int mt = 0; mt < 4; ++mt) {
#pragma unroll
        for (int nt = 0; nt < 4; ++nt)
#pragma unroll
            for (int r = 0; r < 4; ++r) {
                int ee = mt * 16 + quad * 4 + r;
                int ch = nt * 16 + c15;
                float h = fmaxf(acc[mt][nt][r] + bbv[nt], 0.f);
                chunk[(ee & 15) * 64 + ((ch + 4 * ee) & 63)] = __float_as_int(h);
            }
#pragma unroll
        for (int i = 0; i < 16; ++i) {
            int ee = mt * 16 + i;
            float v = __int_as_float(chunk[i * 64 + ((lane + 4 * ee) & 63)]);
            int dd = __builtin_amdgcn_readlane(d_all, ee);
            if (dd != dprev) {
                atomicMax(&agg[(size_t)dprev * 64 + lane], __float_as_uint(run));
                run = 0.f; dprev = dd;
            }
            run = fmaxf(run, v);
        }
    }
    atomicMax(&agg[(size_t)dprev * 64 + lane], __float_as_uint(run));
}

// out[i] = h2[i,:] @ Wl + bl
__global__ __launch_bounds__(256) void final_linear(
    const float* __restrict__ h2, const float* __restrict__ Wl,
    const float* __restrict__ bl, float* __restrict__ out)
{
    int i = blockIdx.x * 256 + threadIdx.x;
    if (i >= NN) return;
    const float4* row = (const float4*)(h2 + (size_t)i * 64);
    float acc = bl[0];
#pragma unroll
    for (int q = 0; q < 16; ++q) {
        float4 v = row[q];
        acc = fmaf(v.x, Wl[q * 4 + 0], acc);
        acc = fmaf(v.y, Wl[q * 4 + 1], acc);
        acc = fmaf(v.z, Wl[q * 4 + 2], acc);
        acc = fmaf(v.w, Wl[q * 4 + 3], acc);
    }
    out[i] = acc;
}

extern "C" void kernel_launch(void* const* d_in, const int* in_sizes, int n_in,
                              void* d_out, int out_size, void* d_ws, size_t ws_size,
                              hipStream_t stream)
{
    const float* x   = (const float*)d_in[0];
    const int*   ei  = (const int*)d_in[1];
    const float* W1a = (const float*)d_in[2];
    const float* b1a = (const float*)d_in[3];
    const float* W1b = (const float*)d_in[4];
    const float* b1b = (const float*)d_in[5];
    const float* W2a = (const float*)d_in[6];
    const float* b2a = (const float*)d_in[7];
    const float* W2b = (const float*)d_in[8];
    const float* b2b = (const float*)d_in[9];
    const float* Wl  = (const float*)d_in[10];
    const float* bl  = (const float*)d_in[11];

    const int* src = ei;
    const int* dst = ei + NE;

    float* ws = (float*)d_ws;
    float* A    = ws + A_OFF;
    float* B    = ws + B_OFF;
    unsigned int* AGG = (unsigned int*)(ws + AGG_OFF);
    int*  gcur  = (int*)(ws + GCUR_OFF);
    int2* p1    = (int2*)(ws + P1_OFF);
    int2* sedge = (int2*)(ws + SEDG_OFF);

    prep_all<<<16, 256, 0, stream>>>(W1a, W1b, W2a, W2b, ws, gcur);
    node_mlp1<<<391, 256, 0, stream>>>(x, ws + W1D_OFF, ws + W1S_OFF, b1a, A, B, (float*)AGG);

    k_bucket <<<782, 256, 0, stream>>>(src, dst, gcur, p1);
    k_sortbkt<<<NB, 256, 0, stream>>>(p1, gcur, sedge);

    edge_layer_mfma<<<NE / 256, 256, 0, stream>>>(A, B, sedge,
                                                  (const int*)(ws + WB1F_OFF), b1b, AGG);

    node_mlp2<<<391, 256, 0, stream>>>((float*)AGG, ws + W2D_OFF, ws + W2S_OFF, b2a, A, B);

    edge_layer_mfma<<<NE / 256, 256, 0, stream>>>(A, B, sedge,
                                                  (const int*)(ws + WB2F_OFF), b2b, AGG);

    final_linear<<<391, 256, 0, stream>>>((const float*)AGG, Wl, bl, (float*)d_out);
}

// Round 7
// 444.289 us; speedup vs baseline: 1.3714x; 1.0327x over previous
//
#include <hip/hip_runtime.h>

#define NN 100000
#define NE 1600000
#define N64 (NN * 64)
#define NB 196                        // buckets = dst>>9 (100000/512)
#define CAP 9216                      // bucket capacity (mean 8192, +11 sigma)

typedef __attribute__((ext_vector_type(8))) short bf16x8;
typedef __attribute__((ext_vector_type(4))) float fx4;

// ---- workspace layout (dword offsets) ----
#define W1D_OFF 0
#define W1S_OFF 448
#define W2D_OFF 896
#define W2S_OFF 4992
#define WB1F_OFF 9216                 // packed Wb frags layer1: 4096 dwords
#define WB2F_OFF 13312                // layer2: 4096 dwords
#define GCUR_OFF 17408                // bucket cursors [256]
#define A_OFF   32768
#define B_OFF   (A_OFF + N64)
#define AGG_OFF (B_OFF + N64)
#define P1_OFF  (AGG_OFF + N64)       // int2[NB*CAP] bucket staging
#define SEDG_OFF (P1_OFF + 2 * NB * CAP)  // int2[NE] sorted edges

union FragU { int i[4]; bf16x8 f; };

// One prep kernel: zero bucket cursors, precombine Wa weights, build Wb MFMA frags.
__global__ __launch_bounds__(256) void prep_all(
    const float* __restrict__ W1a, const float* __restrict__ W1b,
    const float* __restrict__ W2a, const float* __restrict__ W2b,
    float* __restrict__ ws, int* __restrict__ gcur)
{
    int t = blockIdx.x * 256 + threadIdx.x;
    if (t < 256) gcur[t] = 0;
    if (t < 448) {
        float top = W1a[t], bot = W1a[448 + t];
        ws[W1D_OFF + t] = top - bot;
        ws[W1S_OFF + t] = bot;
    }
    if (t < 4096) {
        float top = W2a[t], bot = W2a[4096 + t];
        ws[W2D_OFF + t] = top - bot;
        ws[W2S_OFF + t] = bot;
    }
    // Wb fragments (hi/lo truncation split):
    // int4 index r = mat*512 + ks*256 + nt*64 + lane; lane gives k=(lane>>4)*8+j+32ks,
    // n=(lane&15)+16nt, j packed 2 per dword.
    if (t < 2048) {
        int layer = t >> 10;
        int r = t & 1023;
        int ks = (r >> 8) & 1, nt = (r >> 6) & 3, lane = r & 63, mat = r >> 9;
        const float* Wb = layer ? W2b : W1b;
        int* out = (int*)(ws + (layer ? WB2F_OFF : WB1F_OFF));
        int quad = lane >> 4, c = lane & 15, n = nt * 16 + c;
        unsigned dw[4];
#pragma unroll
        for (int d = 0; d < 4; ++d) {
            unsigned v[2];
#pragma unroll
            for (int e = 0; e < 2; ++e) {
                int k = quad * 8 + d * 2 + e + 32 * ks;
                float w = Wb[k * 64 + n];
                unsigned u = __float_as_uint(w);
                if (mat == 0) v[e] = u >> 16;                        // hi = trunc
                else {
                    float lo = w - __uint_as_float(u & 0xFFFF0000u); // exact residual
                    v[e] = __float_as_uint(lo) >> 16;
                }
            }
            dw[d] = (v[1] << 16) | v[0];
        }
        ((int4*)out)[r] = make_int4((int)dw[0], (int)dw[1], (int)dw[2], (int)dw[3]);
    }
}

// A[i] = x_i @ Wd + ba ; B[i] = x_i @ Ws   (7-ch input); also zero AGG row.
__global__ __launch_bounds__(256) void node_mlp1(
    const float* __restrict__ x, const float* __restrict__ Wd,
    const float* __restrict__ Ws, const float* __restrict__ ba,
    float* __restrict__ A, float* __restrict__ Bv, float* __restrict__ agg)
{
    int i = blockIdx.x * 256 + threadIdx.x;
    if (i >= NN) return;
    float xv[7];
#pragma unroll
    for (int k = 0; k < 7; ++k) xv[k] = x[i * 7 + k];
    float4* pa = (float4*)(A + (size_t)i * 64);
    float4* pb = (float4*)(Bv + (size_t)i * 64);
    float4* pz = (float4*)(agg + (size_t)i * 64);
#pragma unroll
    for (int q = 0; q < 16; ++q) pz[q] = make_float4(0.f, 0.f, 0.f, 0.f);
#pragma unroll
    for (int half = 0; half < 2; ++half) {
        float acc[32];
#pragma unroll
        for (int c = 0; c < 32; ++c) acc[c] = ba[half * 32 + c];
#pragma unroll
        for (int k = 0; k < 7; ++k)
#pragma unroll
            for (int c = 0; c < 32; ++c)
                acc[c] = fmaf(xv[k], Wd[k * 64 + half * 32 + c], acc[c]);
#pragma unroll
        for (int q = 0; q < 8; ++q)
            pa[half * 8 + q] = make_float4(acc[q*4], acc[q*4+1], acc[q*4+2], acc[q*4+3]);
#pragma unroll
        for (int c = 0; c < 32; ++c) acc[c] = 0.0f;
#pragma unroll
        for (int k = 0; k < 7; ++k)
#pragma unroll
            for (int c = 0; c < 32; ++c)
                acc[c] = fmaf(xv[k], Ws[k * 64 + half * 32 + c], acc[c]);
#pragma unroll
        for (int q = 0; q < 8; ++q)
            pb[half * 8 + q] = make_float4(acc[q*4], acc[q*4+1], acc[q*4+2], acc[q*4+3]);
    }
}

// A[i] = g_i @ Wd + ba2 ; B[i] = g_i @ Ws ; then zero g row (re-arm AGG for layer 2)
__global__ __launch_bounds__(256) void node_mlp2(
    float* __restrict__ g, const float* __restrict__ Wd,
    const float* __restrict__ Ws, const float* __restrict__ ba2,
    float* __restrict__ A, float* __restrict__ Bv)
{
    int i = blockIdx.x * 256 + threadIdx.x;
    if (i >= NN) return;
    float gv[64];
    float4* pg = (float4*)(g + (size_t)i * 64);
#pragma unroll
    for (int q = 0; q < 16; ++q) {
        float4 v = pg[q];
        gv[q*4+0] = v.x; gv[q*4+1] = v.y; gv[q*4+2] = v.z; gv[q*4+3] = v.w;
    }
#pragma unroll
    for (int q = 0; q < 16; ++q) pg[q] = make_float4(0.f, 0.f, 0.f, 0.f);
    float4* pa = (float4*)(A + (size_t)i * 64);
    float4* pb = (float4*)(Bv + (size_t)i * 64);
#pragma unroll
    for (int half = 0; half < 2; ++half) {
        float acc[32];
#pragma unroll
        for (int c = 0; c < 32; ++c) acc[c] = ba2[half * 32 + c];
#pragma unroll
        for (int j = 0; j < 64; ++j)
#pragma unroll
            for (int c = 0; c < 32; ++c)
                acc[c] = fmaf(gv[j], Wd[j * 64 + half * 32 + c], acc[c]);
#pragma unroll
        for (int q = 0; q < 8; ++q)
            pa[half * 8 + q] = make_float4(acc[q*4], acc[q*4+1], acc[q*4+2], acc[q*4+3]);
#pragma unroll
        for (int c = 0; c < 32; ++c) acc[c] = 0.0f;
#pragma unroll
        for (int j = 0; j < 64; ++j)
#pragma unroll
            for (int c = 0; c < 32; ++c)
                acc[c] = fmaf(gv[j], Ws[j * 64 + half * 32 + c], acc[c]);
#pragma unroll
        for (int q = 0; q < 8; ++q)
            pb[half * 8 + q] = make_float4(acc[q*4], acc[q*4+1], acc[q*4+2], acc[q*4+3]);
    }
}

// ---- two-pass edge sort by dst ----
__global__ __launch_bounds__(256) void k_bucket(
    const int* __restrict__ src, const int* __restrict__ dst,
    int* __restrict__ gcur, int2* __restrict__ p1)
{
    __shared__ int cnt[NB];
    __shared__ int cur[NB];
    const int t = threadIdx.x;
    const int e0 = (blockIdx.x * 256 + t) * 8;
    const bool ok = (e0 < NE);                   // NE % 8 == 0
    if (t < NB) cnt[t] = 0;
    int ss[8], dd[8], bk[8];
    if (ok) {
        int4 d0 = ((const int4*)(dst + e0))[0];
        int4 d1 = ((const int4*)(dst + e0))[1];
        int4 s0 = ((const int4*)(src + e0))[0];
        int4 s1 = ((const int4*)(src + e0))[1];
        dd[0]=d0.x; dd[1]=d0.y; dd[2]=d0.z; dd[3]=d0.w;
        dd[4]=d1.x; dd[5]=d1.y; dd[6]=d1.z; dd[7]=d1.w;
        ss[0]=s0.x; ss[1]=s0.y; ss[2]=s0.z; ss[3]=s0.w;
        ss[4]=s1.x; ss[5]=s1.y; ss[6]=s1.z; ss[7]=s1.w;
    }
    __syncthreads();
    if (ok) {
#pragma unroll
        for (int j = 0; j < 8; ++j) { bk[j] = dd[j] >> 9; atomicAdd(&cnt[bk[j]], 1); }
    }
    __syncthreads();
    if (t < NB) cur[t] = atomicAdd(&gcur[t], cnt[t]);   // reserve block's ranges
    __syncthreads();
    if (ok) {
#pragma unroll
        for (int j = 0; j < 8; ++j) {
            int pos = atomicAdd(&cur[bk[j]], 1);
            p1[(size_t)bk[j] * CAP + pos] = make_int2(ss[j], dd[j]);
        }
    }
}

__global__ __launch_bounds__(256) void k_sortbkt(
    const int2* __restrict__ p1, const int* __restrict__ gcnt,
    int2* __restrict__ sedge)
{
    __shared__ int sz[256];
    __shared__ int cnt[512];
    __shared__ int cur[512];
    __shared__ int pairb[256];
    const int b = blockIdx.x, t = threadIdx.x;
    sz[t] = (t < NB) ? gcnt[t] : 0;
    cnt[t] = 0; cnt[t + 256] = 0;
    __syncthreads();
#pragma unroll
    for (int off = 1; off < 256; off <<= 1) {       // inclusive scan of bucket sizes
        int u = (t >= off) ? sz[t - off] : 0;
        __syncthreads();
        sz[t] += u;
        __syncthreads();
    }
    const int myBase = (b == 0) ? 0 : sz[b - 1];
    const int mySize = gcnt[b];
    const int2* bp = p1 + (size_t)b * CAP;
    for (int i = t; i < mySize; i += 256) atomicAdd(&cnt[bp[i].y & 511], 1);
    __syncthreads();
    pairb[t] = cnt[2 * t] + cnt[2 * t + 1];
    __syncthreads();
#pragma unroll
    for (int off = 1; off < 256; off <<= 1) {       // scan pair-sums
        int u = (t >= off) ? pairb[t - off] : 0;
        __syncthreads();
        pairb[t] += u;
        __syncthreads();
    }
    int ex = (t == 0) ? 0 : pairb[t - 1];
    cur[2 * t] = ex;
    cur[2 * t + 1] = ex + cnt[2 * t];
    __syncthreads();
    for (int i = t; i < mySize; i += 256) {
        int2 e = bp[i];
        int pos = atomicAdd(&cur[e.y & 511], 1);
        sedge[(size_t)myBase + pos] = e;
    }
}

// MFMA edge layer: wave = 32 edges (2 mt tiles). ALL 16 gather float4s issued
// up-front (one vmcnt wait/wave); t=relu(a+b) split to bf16 hi/lo in-register;
// 3-pass split MFMA; epilogue 16-edge LDS chunks + segmented atomicMax.
__global__ __launch_bounds__(256, 3) void edge_layer_mfma(
    const float* __restrict__ A, const float* __restrict__ Bv,
    const int2* __restrict__ se,
    const int* __restrict__ wbf, const float* __restrict__ bb,
    unsigned int* __restrict__ agg)
{
    __shared__ int lds[4][1024];           // per wave: 16-edge epilogue chunk
    const int tid = threadIdx.x;
    const int wv = tid >> 6, lane = tid & 63;
    int* chunk = lds[wv];
    const int quad = lane >> 4, c15 = lane & 15;
    const int base = (blockIdx.x * 4 + wv) * 32;

    int2 ed  = se[base + (lane & 31)];     // this wave's 32 edges (dup in hi half)
    int2 eb0 = se[base + c15];             // fragment-row edge, mt=0 (quad-uniform)
    int2 eb1 = se[base + 16 + c15];        // mt=1

    const float* pa0 = A  + (size_t)eb0.y * 64 + quad * 8;
    const float* pb0 = Bv + (size_t)eb0.x * 64 + quad * 8;
    const float* pa1 = A  + (size_t)eb1.y * 64 + quad * 8;
    const float* pb1 = Bv + (size_t)eb1.x * 64 + quad * 8;

    // front-load ALL gathers: [mt][ks][half]
    float4 ga[2][2][2], gb[2][2][2];
#pragma unroll
    for (int ks = 0; ks < 2; ++ks)
#pragma unroll
        for (int h = 0; h < 2; ++h) {
            ga[0][ks][h] = ((const float4*)(pa0 + ks * 32))[h];
            gb[0][ks][h] = ((const float4*)(pb0 + ks * 32))[h];
            ga[1][ks][h] = ((const float4*)(pa1 + ks * 32))[h];
            gb[1][ks][h] = ((const float4*)(pb1 + ks * 32))[h];
        }

    // t = relu(a+b), pack bf16 hi/lo: frags [mt][ks]
    bf16x8 fah[2][2], fal[2][2];
#pragma unroll
    for (int mt = 0; mt < 2; ++mt)
#pragma unroll
        for (int ks = 0; ks < 2; ++ks) {
            float t[8];
#pragma unroll
            for (int h = 0; h < 2; ++h) {
                float4 a = ga[mt][ks][h], b = gb[mt][ks][h];
                t[h*4+0] = fmaxf(a.x + b.x, 0.f);
                t[h*4+1] = fmaxf(a.y + b.y, 0.f);
                t[h*4+2] = fmaxf(a.z + b.z, 0.f);
                t[h*4+3] = fmaxf(a.w + b.w, 0.f);
            }
            FragU uh, ul;
#pragma unroll
            for (int d2 = 0; d2 < 4; ++d2) {
                unsigned u0 = __float_as_uint(t[2 * d2]);
                unsigned u1 = __float_as_uint(t[2 * d2 + 1]);
                uh.i[d2] = (int)((u1 & 0xFFFF0000u) | (u0 >> 16));
                float l0 = t[2 * d2]     - __uint_as_float(u0 & 0xFFFF0000u);
                float l1 = t[2 * d2 + 1] - __uint_as_float(u1 & 0xFFFF0000u);
                ul.i[d2] = (int)((__float_as_uint(l1) & 0xFFFF0000u) |
                                 (__float_as_uint(l0) >> 16));
            }
            fah[mt][ks] = uh.f; fal[mt][ks] = ul.f;
        }

    fx4 acc[2][4];
#pragma unroll
    for (int mt = 0; mt < 2; ++mt)
#pragma unroll
        for (int nt = 0; nt < 4; ++nt)
            acc[mt][nt] = (fx4){0.f, 0.f, 0.f, 0.f};

#pragma unroll
    for (int ks = 0; ks < 2; ++ks) {
        bf16x8 wh[4], wl[4];
#pragma unroll
        for (int nt = 0; nt < 4; ++nt) {
            int4 v = ((const int4*)wbf)[(ks * 4 + nt) * 64 + lane];          // hi
            FragU u; u.i[0] = v.x; u.i[1] = v.y; u.i[2] = v.z; u.i[3] = v.w;
            wh[nt] = u.f;
            int4 v2 = ((const int4*)wbf)[((2 + ks) * 4 + nt) * 64 + lane];   // lo
            FragU u2; u2.i[0] = v2.x; u2.i[1] = v2.y; u2.i[2] = v2.z; u2.i[3] = v2.w;
            wl[nt] = u2.f;
        }
#pragma unroll
        for (int mt = 0; mt < 2; ++mt)
#pragma unroll
            for (int nt = 0; nt < 4; ++nt) {
                acc[mt][nt] = __builtin_amdgcn_mfma_f32_16x16x32_bf16(fah[mt][ks], wh[nt], acc[mt][nt], 0, 0, 0);
                acc[mt][nt] = __builtin_amdgcn_mfma_f32_16x16x32_bf16(fah[mt][ks], wl[nt], acc[mt][nt], 0, 0, 0);
                acc[mt][nt] = __builtin_amdgcn_mfma_f32_16x16x32_bf16(fal[mt][ks], wh[nt], acc[mt][nt], 0, 0, 0);
            }
    }

    // epilogue: bias+relu, 16-edge LDS chunks (2-way-max bank swizzle), segmented max
    float bbv[4];
#pragma unroll
    for (int nt = 0; nt < 4; ++nt) bbv[nt] = bb[nt * 16 + c15];

    int dprev = __builtin_amdgcn_readlane(ed.y, 0);
    float run = 0.f;
#pragma unroll
    for (int mt = 0; mt < 2; ++mt) {
#pragma unroll
        for (int nt = 0; nt < 4; ++nt)
#pragma unroll
            for (int r = 0; r < 4; ++r) {
                int ee = mt * 16 + quad * 4 + r;
                int ch = nt * 16 + c15;
                float h = fmaxf(acc[mt][nt][r] + bbv[nt], 0.f);
                chunk[(ee & 15) * 64 + ((ch + 4 * ee) & 63)] = __float_as_int(h);
            }
#pragma unroll
        for (int i = 0; i < 16; ++i) {
            int ee = mt * 16 + i;
            float v = __int_as_float(chunk[i * 64 + ((lane + 4 * ee) & 63)]);
            int dd = __builtin_amdgcn_readlane(ed.y, ee);
            if (dd != dprev) {
                atomicMax(&agg[(size_t)dprev * 64 + lane], __float_as_uint(run));
                run = 0.f; dprev = dd;
            }
            run = fmaxf(run, v);
        }
    }
    atomicMax(&agg[(size_t)dprev * 64 + lane], __float_as_uint(run));
}

// out[i] = h2[i,:] @ Wl + bl
__global__ __launch_bounds__(256) void final_linear(
    const float* __restrict__ h2, const float* __restrict__ Wl,
    const float* __restrict__ bl, float* __restrict__ out)
{
    int i = blockIdx.x * 256 + threadIdx.x;
    if (i >= NN) return;
    const float4* row = (const float4*)(h2 + (size_t)i * 64);
    float acc = bl[0];
#pragma unroll
    for (int q = 0; q < 16; ++q) {
        float4 v = row[q];
        acc = fmaf(v.x, Wl[q * 4 + 0], acc);
        acc = fmaf(v.y, Wl[q * 4 + 1], acc);
        acc = fmaf(v.z, Wl[q * 4 + 2], acc);
        acc = fmaf(v.w, Wl[q * 4 + 3], acc);
    }
    out[i] = acc;
}

extern "C" void kernel_launch(void* const* d_in, const int* in_sizes, int n_in,
                              void* d_out, int out_size, void* d_ws, size_t ws_size,
                              hipStream_t stream)
{
    const float* x   = (const float*)d_in[0];
    const int*   ei  = (const int*)d_in[1];
    const float* W1a = (const float*)d_in[2];
    const float* b1a = (const float*)d_in[3];
    const float* W1b = (const float*)d_in[4];
    const float* b1b = (const float*)d_in[5];
    const float* W2a = (const float*)d_in[6];
    const float* b2a = (const float*)d_in[7];
    const float* W2b = (const float*)d_in[8];
    const float* b2b = (const float*)d_in[9];
    const float* Wl  = (const float*)d_in[10];
    const float* bl  = (const float*)d_in[11];

    const int* src = ei;
    const int* dst = ei + NE;

    float* ws = (float*)d_ws;
    float* A    = ws + A_OFF;
    float* B    = ws + B_OFF;
    unsigned int* AGG = (unsigned int*)(ws + AGG_OFF);
    int*  gcur  = (int*)(ws + GCUR_OFF);
    int2* p1    = (int2*)(ws + P1_OFF);
    int2* sedge = (int2*)(ws + SEDG_OFF);

    prep_all<<<16, 256, 0, stream>>>(W1a, W1b, W2a, W2b, ws, gcur);
    node_mlp1<<<391, 256, 0, stream>>>(x, ws + W1D_OFF, ws + W1S_OFF, b1a, A, B, (float*)AGG);

    k_bucket <<<782, 256, 0, stream>>>(src, dst, gcur, p1);
    k_sortbkt<<<NB, 256, 0, stream>>>(p1, gcur, sedge);

    edge_layer_mfma<<<NE / 128, 256, 0, stream>>>(A, B, sedge,
                                                  (const int*)(ws + WB1F_OFF), b1b, AGG);

    node_mlp2<<<391, 256, 0, stream>>>((float*)AGG, ws + W2D_OFF, ws + W2S_OFF, b2a, A, B);

    edge_layer_mfma<<<NE / 128, 256, 0, stream>>>(A, B, sedge,
                                                  (const int*)(ws + WB2F_OFF), b2b, AGG);

    final_linear<<<391, 256, 0, stream>>>((const float*)AGG, Wl, bl, (float*)d_out);
}